// Round 10
// baseline (807.779 us; speedup 1.0000x reference)
//
#include <hip/hip_runtime.h>
#include <hip/hip_bf16.h>
#include <math.h>

// Problem constants
#define B_  8
#define N_  1024
#define C_  12
#define E_  256
#define H_  8
#define D_  32      // E/H
#define L_  4
#define XE_ 1024    // X*E
#define NC_ 5
#define S_  1025    // N+1
#define M_  8200    // B*S
#define EPS_ 1e-5f
#define SP_ 1088    // padded key-stride for vT (17*64, 16B-aligned)

typedef short bf16x8 __attribute__((ext_vector_type(8)));
typedef float f32x4 __attribute__((ext_vector_type(4)));
typedef __hip_bfloat16 bf16;

// ---------------- Embedding (wave per token): x@W+b -> LN -> GELU ----------
__global__ __launch_bounds__(256) void embed4_kernel(
    const float* __restrict__ x, const float* __restrict__ Wemb,
    const float* __restrict__ bemb, const float* __restrict__ g,
    const float* __restrict__ be, const float* __restrict__ cls,
    float* __restrict__ h)
{
    int wave = threadIdx.x >> 6, lane = threadIdx.x & 63;
    int t = blockIdx.x * 4 + wave;          // M_ = 4*2050 exactly
    int b = t / S_, s = t % S_;
    long base = (long)t * E_ + lane * 4;

    if (s == 0) {                            // cls token raw
        *(float4*)(h + base) = *(const float4*)(cls + lane * 4);
        return;
    }
    const float* xr = x + ((long)b * N_ + (s - 1)) * C_;
    float xv[C_];
#pragma unroll
    for (int c = 0; c < C_; ++c) xv[c] = xr[c];   // wave-broadcast loads

    float4 acc = *(const float4*)(bemb + lane * 4);
#pragma unroll
    for (int c = 0; c < C_; ++c) {
        float4 w = *(const float4*)(Wemb + c * E_ + lane * 4);
        acc.x += xv[c] * w.x; acc.y += xv[c] * w.y;
        acc.z += xv[c] * w.z; acc.w += xv[c] * w.w;
    }
    float sum = acc.x + acc.y + acc.z + acc.w;
    float sq  = acc.x*acc.x + acc.y*acc.y + acc.z*acc.z + acc.w*acc.w;
#pragma unroll
    for (int off = 1; off < 64; off <<= 1) {
        sum += __shfl_xor(sum, off);
        sq  += __shfl_xor(sq,  off);
    }
    float mean = sum * (1.0f / E_);
    float var  = sq * (1.0f / E_) - mean * mean;
    float rstd = rsqrtf(var + EPS_);
    float4 gg = *(const float4*)(g + lane * 4);
    float4 bb = *(const float4*)(be + lane * 4);
    float4 o;
    float v;
    v = (acc.x - mean) * rstd * gg.x + bb.x; o.x = 0.5f * v * (1.0f + erff(v * 0.70710678118f));
    v = (acc.y - mean) * rstd * gg.y + bb.y; o.y = 0.5f * v * (1.0f + erff(v * 0.70710678118f));
    v = (acc.z - mean) * rstd * gg.z + bb.z; o.z = 0.5f * v * (1.0f + erff(v * 0.70710678118f));
    v = (acc.w - mean) * rstd * gg.w + bb.w; o.w = 0.5f * v * (1.0f + erff(v * 0.70710678118f));
    *(float4*)(h + base) = o;
}

// ------------- LN (wave per token): optional h+=pos, y=bf16(LN(h)) ---------
__global__ __launch_bounds__(256) void ln4_kernel(
    float* __restrict__ h, const float* __restrict__ pos,
    const float* __restrict__ g, const float* __restrict__ bb,
    bf16* __restrict__ y)
{
    int wave = threadIdx.x >> 6, lane = threadIdx.x & 63;
    int t = blockIdx.x * 4 + wave;
    int s = t % S_;
    long base = (long)t * E_ + lane * 4;

    float4 v = *(const float4*)(h + base);
    if (pos) {
        float4 pv = *(const float4*)(pos + (long)s * E_ + lane * 4);
        v.x += pv.x; v.y += pv.y; v.z += pv.z; v.w += pv.w;
        *(float4*)(h + base) = v;
    }
    float sum = v.x + v.y + v.z + v.w;
    float sq  = v.x*v.x + v.y*v.y + v.z*v.z + v.w*v.w;
#pragma unroll
    for (int off = 1; off < 64; off <<= 1) {
        sum += __shfl_xor(sum, off);
        sq  += __shfl_xor(sq,  off);
    }
    float mean = sum * (1.0f / E_);
    float var  = sq * (1.0f / E_) - mean * mean;
    float rstd = rsqrtf(var + EPS_);
    float4 gg = *(const float4*)(g + lane * 4);
    float4 b4 = *(const float4*)(bb + lane * 4);
    bf16 o[4];
    o[0] = __float2bfloat16((v.x - mean) * rstd * gg.x + b4.x);
    o[1] = __float2bfloat16((v.y - mean) * rstd * gg.y + b4.y);
    o[2] = __float2bfloat16((v.z - mean) * rstd * gg.z + b4.z);
    o[3] = __float2bfloat16((v.w - mean) * rstd * gg.w + b4.w);
    *(uint2*)(y + base) = *(uint2*)o;
}

// ---------- Single-launch weight pack (LDS 32x32 transpose) ----------------
__global__ __launch_bounds__(256) void pack_all(
    const float* __restrict__ Wq, const float* __restrict__ Wk,
    const float* __restrict__ Wv, const float* __restrict__ bq,
    const float* __restrict__ bk, const float* __restrict__ bv,
    const float* __restrict__ Wo, const float* __restrict__ W1,
    const float* __restrict__ W2,
    bf16* __restrict__ Wqkvt, float* __restrict__ bqkv,
    bf16* __restrict__ Wot, bf16* __restrict__ W1t, bf16* __restrict__ W2t)
{
    __shared__ float tile[32][33];
    int id = blockIdx.x;
    int tx = threadIdx.x & 31, ty = threadIdx.x >> 5;   // 32x8
    const float* src; bf16* dst;
    int c0, k0, Nsrc, Kd, row0;

    if (id < 768) {                       // QKV: 4l x 8k x 24n
        int l = id / 192, r = id % 192;
        int nt = r % 24, kt2 = r / 24;
        int n0 = nt * 32; k0 = kt2 * 32;
        Nsrc = 256; Kd = 256; row0 = n0;
        if (n0 < 256)      { src = Wq + (long)l * 65536; c0 = n0; }
        else if (n0 < 512) { src = Wk + (long)l * 65536; c0 = n0 - 256; }
        else               { src = Wv + (long)l * 65536; c0 = n0 - 512; }
        dst = Wqkvt + (long)l * 768 * 256;
        if (kt2 == 0 && ty == 0) {
            const float* bsrc = (n0 < 256) ? bq + l * 256 + c0
                              : (n0 < 512) ? bk + l * 256 + c0 : bv + l * 256 + c0;
            bqkv[l * 768 + n0 + tx] = bsrc[tx];
        }
    } else if (id < 1024) {               // Wo: 4l x 8k x 8n
        int r = id - 768; int l = r / 64; r %= 64;
        int nt = r & 7, kt2 = r >> 3;
        c0 = nt * 32; k0 = kt2 * 32; Nsrc = 256; Kd = 256; row0 = c0;
        src = Wo + (long)l * 65536; dst = Wot + (long)l * 65536;
    } else if (id < 2048) {               // W1: 4l x 8k x 32n
        int r = id - 1024; int l = r / 256; r %= 256;
        int nt = r % 32, kt2 = r / 32;
        c0 = nt * 32; k0 = kt2 * 32; Nsrc = 1024; Kd = 256; row0 = c0;
        src = W1 + (long)l * 262144; dst = W1t + (long)l * 262144;
    } else {                              // W2: 4l x 32k x 8n
        int r = id - 2048; int l = r / 256; r %= 256;
        int nt = r & 7, kt2 = r >> 3;
        c0 = nt * 32; k0 = kt2 * 32; Nsrc = 256; Kd = 1024; row0 = c0;
        src = W2 + (long)l * 262144; dst = W2t + (long)l * 262144;
    }
#pragma unroll
    for (int i = 0; i < 4; ++i)
        tile[ty + i * 8][tx] = src[(long)(k0 + ty + i * 8) * Nsrc + c0 + tx];
    __syncthreads();
#pragma unroll
    for (int i = 0; i < 4; ++i)
        dst[(long)(row0 + ty + i * 8) * Kd + k0 + tx] = __float2bfloat16(tile[tx][ty + i * 8]);
}

// ---- bf16 MFMA GEMM 128x128 tile, double-buffered; optional vT scatter ----
__global__ __launch_bounds__(256) void gemm_bf16_128(
    const bf16* __restrict__ A, const bf16* __restrict__ Wt,
    const float* __restrict__ bias,
    bf16* __restrict__ outB, bf16* __restrict__ vTout,
    int M, int K, int N, int act)
{
    __shared__ bf16 As[2][128 * 72];
    __shared__ bf16 Bs[2][128 * 72];
    int tid = threadIdx.x;
    int wave = tid >> 6, lane = tid & 63;
    int quad = lane >> 4, l16 = lane & 15;
    int wr = (wave >> 1) * 64, wc = (wave & 1) * 64;
    int row0 = blockIdx.y * 128;
    int col0 = blockIdx.x * 128;

    f32x4 acc[4][4];
#pragma unroll
    for (int i = 0; i < 4; ++i)
#pragma unroll
        for (int j = 0; j < 4; ++j) acc[i][j] = (f32x4){0.f,0.f,0.f,0.f};
    uint4 z4 = make_uint4(0,0,0,0);

    int nk = K >> 6;
    {   // prologue: stage k-tile 0 into buffer 0
#pragma unroll
        for (int c = tid; c < 1024; c += 256) {
            int r = c >> 3, off = (c & 7) * 8;
            uint4 val = z4;
            int gr = row0 + r;
            if (gr < M) val = *(const uint4*)(A + (long)gr * K + off);
            *(uint4*)&As[0][r * 72 + off] = val;
            *(uint4*)&Bs[0][r * 72 + off] = *(const uint4*)(Wt + (long)(col0 + r) * K + off);
        }
    }
    for (int kt = 0; kt < nk; ++kt) {
        __syncthreads();
        if (kt < nk - 1) {
            int k1 = (kt + 1) << 6;
            int nb = (kt & 1) ^ 1;
#pragma unroll
            for (int c = tid; c < 1024; c += 256) {
                int r = c >> 3, off = (c & 7) * 8;
                uint4 val = z4;
                int gr = row0 + r;
                if (gr < M) val = *(const uint4*)(A + (long)gr * K + k1 + off);
                *(uint4*)&As[nb][r * 72 + off] = val;
                *(uint4*)&Bs[nb][r * 72 + off] = *(const uint4*)(Wt + (long)(col0 + r) * K + k1 + off);
            }
        }
        int buf = kt & 1;
#pragma unroll
        for (int ks = 0; ks < 64; ks += 32) {
            bf16x8 af[4], bfr[4];
#pragma unroll
            for (int i = 0; i < 4; ++i)
                af[i] = *(const bf16x8*)&As[buf][(wr + i * 16 + l16) * 72 + ks + quad * 8];
#pragma unroll
            for (int j = 0; j < 4; ++j)
                bfr[j] = *(const bf16x8*)&Bs[buf][(wc + j * 16 + l16) * 72 + ks + quad * 8];
#pragma unroll
            for (int i = 0; i < 4; ++i)
#pragma unroll
                for (int j = 0; j < 4; ++j)
                    acc[i][j] = __builtin_amdgcn_mfma_f32_16x16x32_bf16(af[i], bfr[j], acc[i][j], 0, 0, 0);
        }
    }
#pragma unroll
    for (int i = 0; i < 4; ++i) {
#pragma unroll
        for (int j = 0; j < 4; ++j) {
            int col = col0 + wc + j * 16 + l16;
#pragma unroll
            for (int r = 0; r < 4; ++r) {
                int m = row0 + wr + i * 16 + quad * 4 + r;
                if (m >= M) continue;
                float v = acc[i][j][r] + bias[col];
                if (act == 1) v = 0.5f * v * (1.0f + erff(v * 0.70710678118f));
                bf16 bvv = __float2bfloat16(v);
                outB[(long)m * N + col] = bvv;
                if (vTout && col >= 512) {   // V cols -> vT[bh][d][key]
                    int b2 = m / S_;
                    int key = m - b2 * S_;
                    int cc = col - 512;
                    vTout[((long)(b2 * 8 + (cc >> 5)) * 32 + (cc & 31)) * SP_ + key] = bvv;
                }
            }
        }
    }
}

// ------- bf16 MFMA GEMM 64x64 tile, double-buffered: act(A@Wt^T+b)[+res] ---
__global__ __launch_bounds__(256) void gemm_bf16(
    const bf16* __restrict__ A, const bf16* __restrict__ Wt,
    const float* __restrict__ bias, const float* __restrict__ res,
    float* __restrict__ outF, bf16* __restrict__ outB,
    int M, int K, int N, int act)
{
    __shared__ bf16 As[2][64 * 72];
    __shared__ bf16 Bs[2][64 * 72];
    int tid = threadIdx.x;
    int wave = tid >> 6, lane = tid & 63;
    int quad = lane >> 4, l16 = lane & 15;
    int row0 = blockIdx.y * 64;
    int col0 = blockIdx.x * 64;
    uint4 z4 = make_uint4(0,0,0,0);

    f32x4 acc[4] = {{0.f,0.f,0.f,0.f},{0.f,0.f,0.f,0.f},{0.f,0.f,0.f,0.f},{0.f,0.f,0.f,0.f}};
    int nk = K >> 6;

    {   // stage tile 0
        for (int c = tid; c < 512; c += 256) {
            int r = c >> 3, off = (c & 7) * 8;
            uint4 va = z4;
            int gr = row0 + r;
            if (gr < M) va = *(const uint4*)(A + (long)gr * K + off);
            *(uint4*)&As[0][r * 72 + off] = va;
            *(uint4*)&Bs[0][r * 72 + off] = *(const uint4*)(Wt + (long)(col0 + r) * K + off);
        }
    }
    for (int kt = 0; kt < nk; ++kt) {
        __syncthreads();
        if (kt < nk - 1) {
            int k1 = (kt + 1) << 6;
            int nb = (kt & 1) ^ 1;
            for (int c = tid; c < 512; c += 256) {
                int r = c >> 3, off = (c & 7) * 8;
                uint4 va = z4;
                int gr = row0 + r;
                if (gr < M) va = *(const uint4*)(A + (long)gr * K + k1 + off);
                *(uint4*)&As[nb][r * 72 + off] = va;
                *(uint4*)&Bs[nb][r * 72 + off] = *(const uint4*)(Wt + (long)(col0 + r) * K + k1 + off);
            }
        }
        int buf = kt & 1;
#pragma unroll
        for (int ks = 0; ks < 64; ks += 32) {
            bf16x8 af = *(const bf16x8*)&As[buf][(wave * 16 + l16) * 72 + ks + quad * 8];
#pragma unroll
            for (int nt = 0; nt < 4; ++nt) {
                bf16x8 bf = *(const bf16x8*)&Bs[buf][(nt * 16 + l16) * 72 + ks + quad * 8];
                acc[nt] = __builtin_amdgcn_mfma_f32_16x16x32_bf16(af, bf, acc[nt], 0, 0, 0);
            }
        }
    }
#pragma unroll
    for (int nt = 0; nt < 4; ++nt) {
        int col = col0 + nt * 16 + l16;
#pragma unroll
        for (int r = 0; r < 4; ++r) {
            int m = row0 + wave * 16 + quad * 4 + r;
            if (m >= M) continue;
            float v = acc[nt][r] + bias[col];
            if (act == 1) v = 0.5f * v * (1.0f + erff(v * 0.70710678118f));
            if (res)  v += res[(long)m * N + col];
            if (outF) outF[(long)m * N + col] = v;
            if (outB) outB[(long)m * N + col] = __float2bfloat16(v);
        }
    }
}

// --------------- MFMA flash attention v5: 128-q tiles + split-K=2 ----------
// blockIdx.x = bh*18 + qt*2 + ks. ks=0: key tiles 0..8; ks=1: tiles 9..16.
// Writes UNNORMALIZED partial O (bf16) and partial l-sums (fp32, per q,head).
#define NQT4 9   // ceil(S_/128)
__global__ __launch_bounds__(256) void attn_mfma5_kernel(
    const bf16* __restrict__ qkv, const bf16* __restrict__ vT,
    bf16* __restrict__ Opart, float* __restrict__ lpart)
{
    __shared__ bf16 Ks[2][64 * 40];    // [key][d], row 80 B
    __shared__ bf16 Vs[2][32 * 80];    // [d][key], row 160 B
    __shared__ bf16 Pa[4][32 * 80];    // per-wave P [q][key], row 160 B

    int tid = threadIdx.x;
    int wave = tid >> 6, lane = tid & 63;
    int quad = lane >> 4, l16 = lane & 15;
    int blk = blockIdx.x;
    int bh = blk / 18;
    int r2 = blk % 18;
    int qt = r2 >> 1, ks = r2 & 1;
    int b = bh >> 3, hh = bh & 7;
    int q0 = qt * 128;
    int kt0 = ks ? 9 : 0;
    int kt1 = ks ? 17 : 9;
    long bS = (long)b * S_;
    bf16* Pw = Pa[wave];
    const bf16* vTb = vT + (long)bh * 32 * SP_;
    uint4 z4 = make_uint4(0,0,0,0);

    int skey = tid >> 2, sdg = tid & 3;          // K: 64 keys x 4 d-chunks
    int svd = tid >> 3, svc = tid & 7;           // V: 32 d-rows x 8 key-chunks

    // Q-frags x2 (rows q0+wave*32+f*16+l16)
    bf16x8 aq[2];
#pragma unroll
    for (int f = 0; f < 2; ++f) {
        bf16x8 a = {0,0,0,0,0,0,0,0};
        int gq = q0 + wave * 32 + f * 16 + l16;
        if (gq < S_) a = *(const bf16x8*)(qkv + (bS + gq) * 768 + hh * 32 + quad * 8);
        aq[f] = a;
    }

    f32x4 o00 = {0.f,0.f,0.f,0.f}, o01 = {0.f,0.f,0.f,0.f};
    f32x4 o10 = {0.f,0.f,0.f,0.f}, o11 = {0.f,0.f,0.f,0.f};
    float lsum[2][4] = {{0.f,0.f,0.f,0.f},{0.f,0.f,0.f,0.f}};
    f32x4 zf = {0.f,0.f,0.f,0.f};

    {   // prologue: stage tile kt0
        int gk = kt0 * 64 + skey;
        uint4 kv = z4;
        if (gk < S_) kv = *(const uint4*)(qkv + (bS + gk) * 768 + 256 + hh * 32 + sdg * 8);
        *(uint4*)&Ks[0][skey * 40 + sdg * 8] = kv;
        *(uint4*)&Vs[0][svd * 80 + svc * 8] =
            *(const uint4*)(vTb + (long)svd * SP_ + kt0 * 64 + svc * 8);
    }

    for (int kt = kt0; kt < kt1; ++kt) {
        int j0 = kt * 64;
        int bb = (kt - kt0) & 1;
        __syncthreads();

        if (kt + 1 < kt1) {
            int j1 = j0 + 64;
            int gk = j1 + skey;
            uint4 kv = z4;
            if (gk < S_) kv = *(const uint4*)(qkv + (bS + gk) * 768 + 256 + hh * 32 + sdg * 8);
            *(uint4*)&Ks[bb ^ 1][skey * 40 + sdg * 8] = kv;
            *(uint4*)&Vs[bb ^ 1][svd * 80 + svc * 8] =
                *(const uint4*)(vTb + (long)svd * SP_ + j1 + svc * 8);
        }

        // K frags once, used by both Q-frags
        bf16x8 bk[4];
#pragma unroll
        for (int t4 = 0; t4 < 4; ++t4)
            bk[t4] = *(const bf16x8*)&Ks[bb][(t4 * 16 + l16) * 40 + quad * 8];

#pragma unroll
        for (int f = 0; f < 2; ++f) {
            f32x4 sc[4];
#pragma unroll
            for (int t4 = 0; t4 < 4; ++t4)
                sc[t4] = __builtin_amdgcn_mfma_f32_16x16x32_bf16(aq[f], bk[t4], zf, 0, 0, 0);
            if (kt < 16) {               // full tile: no validity masking
#pragma unroll
                for (int t4 = 0; t4 < 4; ++t4)
#pragma unroll
                    for (int r = 0; r < 4; ++r) {
                        float p = __expf(fminf(sc[t4][r], 60.f));
                        lsum[f][r] += p;
                        Pw[(f * 16 + quad * 4 + r) * 80 + t4 * 16 + l16] = __float2bfloat16(p);
                    }
            } else {                     // masked tail tile
#pragma unroll
                for (int t4 = 0; t4 < 4; ++t4) {
                    bool valid = (j0 + t4 * 16 + l16) < S_;
#pragma unroll
                    for (int r = 0; r < 4; ++r) {
                        float p = valid ? __expf(fminf(sc[t4][r], 60.f)) : 0.f;
                        lsum[f][r] += p;
                        Pw[(f * 16 + quad * 4 + r) * 80 + t4 * 16 + l16] = __float2bfloat16(p);
                    }
                }
            }
        }
        // PV: shared V frags across both Q-frags
#pragma unroll
        for (int ks2 = 0; ks2 < 64; ks2 += 32) {
            bf16x8 bv0 = *(const bf16x8*)&Vs[bb][l16 * 80 + ks2 + quad * 8];
            bf16x8 bv1 = *(const bf16x8*)&Vs[bb][(16 + l16) * 80 + ks2 + quad * 8];
            bf16x8 ap0 = *(const bf16x8*)&Pw[l16 * 80 + ks2 + quad * 8];
            bf16x8 ap1 = *(const bf16x8*)&Pw[(16 + l16) * 80 + ks2 + quad * 8];
            o00 = __builtin_amdgcn_mfma_f32_16x16x32_bf16(ap0, bv0, o00, 0, 0, 0);
            o01 = __builtin_amdgcn_mfma_f32_16x16x32_bf16(ap0, bv1, o01, 0, 0, 0);
            o10 = __builtin_amdgcn_mfma_f32_16x16x32_bf16(ap1, bv0, o10, 0, 0, 0);
            o11 = __builtin_amdgcn_mfma_f32_16x16x32_bf16(ap1, bv1, o11, 0, 0, 0);
        }
    }

    // store partial O (unnormalized, bf16) + partial l (fp32)
    bf16* Op = Opart + (long)ks * M_ * 256;
    float* lp = lpart + (long)ks * M_ * 8;
#pragma unroll
    for (int f = 0; f < 2; ++f) {
        f32x4 oa = f ? o10 : o00;
        f32x4 obv = f ? o11 : o01;
#pragma unroll
        for (int r = 0; r < 4; ++r) {
            float t = lsum[f][r];
            t += __shfl_xor(t, 1); t += __shfl_xor(t, 2);
            t += __shfl_xor(t, 4); t += __shfl_xor(t, 8);
            int gq = q0 + wave * 32 + f * 16 + quad * 4 + r;
            if (gq < S_) {
                long base = (bS + gq) * 256 + hh * 32;
                Op[base + l16]      = __float2bfloat16(oa[r]);
                Op[base + 16 + l16] = __float2bfloat16(obv[r]);
                if (l16 == 0) lp[(bS + gq) * 8 + hh] = t;
            }
        }
    }
}

// --------------- Split-K combine: obuf = (O0+O1)/((l0+l1)*16) --------------
__global__ __launch_bounds__(256) void attn_combine(
    const bf16* __restrict__ Opart, const float* __restrict__ lpart,
    bf16* __restrict__ ob)
{
    int wave = threadIdx.x >> 6, lane = threadIdx.x & 63;
    int t = blockIdx.x * 4 + wave;
    int head = lane >> 3;                 // lane*4 / 32
    long base = (long)t * 256 + lane * 4;

    float l0 = lpart[(long)t * 8 + head];
    float l1 = lpart[(long)M_ * 8 + (long)t * 8 + head];
    float inv = 1.0f / ((l0 + l1) * 16.0f);

    uint2 u0 = *(const uint2*)(Opart + base);
    uint2 u1 = *(const uint2*)(Opart + (long)M_ * 256 + base);
    const bf16* p0 = (const bf16*)&u0;
    const bf16* p1 = (const bf16*)&u1;
    bf16 o[4];
#pragma unroll
    for (int i = 0; i < 4; ++i)
        o[i] = __float2bfloat16((__bfloat162float(p0[i]) + __bfloat162float(p1[i])) * inv);
    *(uint2*)(ob + base) = *(uint2*)o;
}

// --------------- Pool: partial[b][sc][e] = sum over 65-row chunk -----------
__global__ __launch_bounds__(256) void pool_kernel(const float* __restrict__ h,
                                                   float* __restrict__ partial)
{
    int b = blockIdx.x >> 4, sc = blockIdx.x & 15;
    int e = threadIdx.x;
    int s0 = sc * 65, s1 = min(S_, s0 + 65);
    float acc = 0.f;
    for (int s = s0; s < s1; ++s) acc += h[((long)b * S_ + s) * E_ + e];
    partial[((long)b * 16 + sc) * E_ + e] = acc;
}

// --------------- Classifier final: Linear -> LN -> Linear -----------------
__global__ __launch_bounds__(256) void cls_final(
    const float* __restrict__ partial, const float* __restrict__ Wc1,
    const float* __restrict__ bc1, const float* __restrict__ lg,
    const float* __restrict__ lb, const float* __restrict__ Wc2,
    const float* __restrict__ bc2, float* __restrict__ out)
{
    int b = blockIdx.x;
    int e = threadIdx.x;
    __shared__ float p[256];
    __shared__ float red[256];
    __shared__ float lnv[256];

    float acc = 0.f;
#pragma unroll
    for (int sc = 0; sc < 16; ++sc) acc += partial[((long)b * 16 + sc) * E_ + e];
    p[e] = acc * (1.0f / S_);
    __syncthreads();

    float c1 = bc1[e];
    for (int kk = 0; kk < E_; ++kk) c1 += p[kk] * Wc1[kk * E_ + e];

    red[e] = c1; __syncthreads();
    for (int st = 128; st; st >>= 1) { if (e < st) red[e] += red[e + st]; __syncthreads(); }
    float mean = red[0] * (1.0f / E_); __syncthreads();
    float d = c1 - mean;
    red[e] = d * d; __syncthreads();
    for (int st = 128; st; st >>= 1) { if (e < st) red[e] += red[e + st]; __syncthreads(); }
    float var = red[0] * (1.0f / E_);
    lnv[e] = d * rsqrtf(var + EPS_) * lg[e] + lb[e];
    __syncthreads();

    if (e < NC_) {
        float oacc = bc2[e];
        for (int kk = 0; kk < E_; ++kk) oacc += lnv[kk] * Wc2[kk * NC_ + e];
        out[b * NC_ + e] = oacc;
    }
}

extern "C" void kernel_launch(void* const* d_in, const int* in_sizes, int n_in,
                              void* d_out, int out_size, void* d_ws, size_t ws_size,
                              hipStream_t stream)
{
    const float* x      = (const float*)d_in[0];
    const float* W_emb  = (const float*)d_in[1];
    const float* b_emb  = (const float*)d_in[2];
    const float* g_emb  = (const float*)d_in[3];
    const float* be_emb = (const float*)d_in[4];
    const float* cls    = (const float*)d_in[5];
    const float* pos    = (const float*)d_in[6];
    const float* ln1_g  = (const float*)d_in[7];
    const float* ln1_b  = (const float*)d_in[8];
    const float* Wq     = (const float*)d_in[9];
    const float* bq     = (const float*)d_in[10];
    const float* Wk     = (const float*)d_in[11];
    const float* bk     = (const float*)d_in[12];
    const float* Wv     = (const float*)d_in[13];
    const float* bv     = (const float*)d_in[14];
    const float* Wo     = (const float*)d_in[15];
    const float* bo     = (const float*)d_in[16];
    const float* ln2_g  = (const float*)d_in[17];
    const float* ln2_b  = (const float*)d_in[18];
    const float* W1     = (const float*)d_in[19];
    const float* b1     = (const float*)d_in[20];
    const float* W2     = (const float*)d_in[21];
    const float* b2     = (const float*)d_in[22];
    const float* Wc1    = (const float*)d_in[23];
    const float* bc1    = (const float*)d_in[24];
    const float* lnc_g  = (const float*)d_in[25];
    const float* lnc_b  = (const float*)d_in[26];
    const float* Wc2    = (const float*)d_in[27];
    const float* bc2    = (const float*)d_in[28];
    float* out = (float*)d_out;

    char* p = (char*)d_ws;
    float* h     = (float*)p; p += (long)M_ * 256 * 4;
    bf16* y      = (bf16*)p;  p += (long)M_ * 256 * 2;
    bf16* qkv    = (bf16*)p;  p += (long)M_ * 768 * 2;
    bf16* obuf   = (bf16*)p;  p += (long)M_ * 256 * 2;
    bf16* tb     = (bf16*)p;  p += (long)M_ * 1024 * 2;
    bf16* Wqkvt  = (bf16*)p;  p += (long)L_ * 768 * 256 * 2;
    bf16* Wot    = (bf16*)p;  p += (long)L_ * 256 * 256 * 2;
    bf16* W1t    = (bf16*)p;  p += (long)L_ * 1024 * 256 * 2;
    bf16* W2t    = (bf16*)p;  p += (long)L_ * 256 * 1024 * 2;
    float* bqkv  = (float*)p; p += (long)L_ * 768 * 4;
    float* pool  = (float*)p; p += (long)B_ * 16 * 256 * 4;
    bf16* vT     = (bf16*)p;  p += (long)64 * 32 * SP_ * 2;
    bf16* Opart  = (bf16*)p;  p += (long)2 * M_ * 256 * 2;
    float* lpart = (float*)p; p += (long)2 * M_ * 8 * 4;

    // ---- weight packing (1 launch) ----
    pack_all<<<3072, 256, 0, stream>>>(Wq, Wk, Wv, bq, bk, bv, Wo, W1, W2,
                                       Wqkvt, bqkv, Wot, W1t, W2t);

    embed4_kernel<<<M_ / 4, 256, 0, stream>>>(x, W_emb, b_emb, g_emb, be_emb, cls, h);

    dim3 gQKV(6, 65), gMLP1(8, 65), gEE(4, 129);
    for (int l = 0; l < L_; ++l) {
        // h += pos; y = LN1(h)
        ln4_kernel<<<M_ / 4, 256, 0, stream>>>(h, pos, ln1_g + l * E_, ln1_b + l * E_, y);
        // qkv = y @ Wqkv + b (V cols also -> vT, transposed)
        gemm_bf16_128<<<gQKV, 256, 0, stream>>>(y, Wqkvt + (long)l * 768 * 256, bqkv + l * 768,
                                                qkv, vT, M_, 256, 768, 0);
        // attention: split-K=2 partials, then combine
        attn_mfma5_kernel<<<64 * NQT4 * 2, 256, 0, stream>>>(qkv, vT, Opart, lpart);
        attn_combine<<<M_ / 4, 256, 0, stream>>>(Opart, lpart, obuf);
        // h += o @ Wo + bo
        gemm_bf16<<<gEE, 256, 0, stream>>>(obuf, Wot + (long)l * 65536, bo + l * E_,
                                           h, h, nullptr, M_, 256, 256, 0);
        // y = LN2(h); tb = GELU(y @ W1 + b1)
        ln4_kernel<<<M_ / 4, 256, 0, stream>>>(h, nullptr, ln2_g + l * E_, ln2_b + l * E_, y);
        gemm_bf16_128<<<gMLP1, 256, 0, stream>>>(y, W1t + (long)l * 262144, b1 + l * XE_,
                                                 tb, nullptr, M_, 256, 1024, 1);
        // h += tb @ W2 + b2
        gemm_bf16<<<gEE, 256, 0, stream>>>(tb, W2t + (long)l * 262144, b2 + l * E_,
                                           h, h, nullptr, M_, 1024, 256, 0);
    }

    pool_kernel<<<B_ * 16, 256, 0, stream>>>(h, pool);
    cls_final<<<B_, 256, 0, stream>>>(pool, Wc1, bc1, lnc_g, lnc_b, Wc2, bc2, out);
}